// Round 1
// baseline (154.049 us; speedup 1.0000x reference)
//
#include <hip/hip_runtime.h>
#include <hip/hip_bf16.h>
#include <hip/hip_cooperative_groups.h>

namespace cg = cooperative_groups;

// ---------------- problem constants ----------------
#define Bn    8
#define MO    12
#define Dd    512
#define NOBJ  37
#define NACT  6
#define NTRS  3
#define EMB   128
#define NAA   100
#define NCLS  300
#define Kk    72            // MO*NACT
#define Pp    5112          // Kk*(Kk-1)
#define HALF  768           // Dd + 2*EMB
#define FD    1536          // 2*HALF

// output layout (concatenated return order)
#define OUT_FINAL 0
#define OUT_PLOG  (Bn*NCLS)                       // 2400
#define OUT_TTGT  (OUT_PLOG + Bn*Pp*NTRS)         // 125088
#define OUT_ACT   (OUT_TTGT + Bn*Pp*NTRS)         // 247776
#define OUT_OBJ   (OUT_ACT + Bn*Kk)               // 248352

// ---------------- workspace layout (4-byte units) ----------------
// NE dropped (lazy); obj/act logits read back from `out` directly.
#define WS_LINP 0                                 // [B,MO,6] (th = t*2+h)
#define WS_EO   (WS_LINP + Bn*MO*6)               // [NOBJ,6]        576
#define WS_EA   (WS_EO + NOBJ*6)                  // [NACT,6]        798
#define WS_INV  (WS_EA + NACT*6)                  // [3]             834

// ---------------- phase-A wave-task ranges ----------------
#define T_OBJ  (Bn*MO*NOBJ)                       // 3552
#define T_ACT  (T_OBJ + Bn*Kk)                    // 4128
#define T_LINP (T_ACT + Bn*MO*6)                  // 4704
#define T_EO   (T_LINP + NOBJ*6)                  // 4926
#define T_EA   (T_EO + NACT*6)                    // 4962
#define T_INV  (T_EA + NTRS)                      // 4965

#define GRID   256
#define NSLICE 20

// monotonic float <-> uint; 0u is below any finite mapped value = "empty"
__device__ __forceinline__ unsigned fmap(float f) {
  unsigned u = __float_as_uint(f);
  return (u & 0x80000000u) ? ~u : (u | 0x80000000u);
}
__device__ __forceinline__ float funmap(unsigned u) {
  return __uint_as_float((u & 0x80000000u) ? (u & 0x7fffffffu) : ~u);
}

__device__ __forceinline__ float wreduce(float v) {
#pragma unroll
  for (int off = 32; off > 0; off >>= 1) v += __shfl_xor(v, off, 64);
  return v;
}

// 512-dot with x preloaded (lane holds float4 #lane, #(lane+64))
__device__ __forceinline__ float dotW(const float* __restrict__ wrow,
                                      float4 x0, float4 x1, int lane) {
  const float4* w4 = (const float4*)wrow;
  float4 w0 = w4[lane], w1 = w4[lane + 64];
  float s0 = fmaf(w0.x, x0.x, fmaf(w0.y, x0.y, fmaf(w0.z, x0.z, w0.w * x0.w)));
  float s1 = fmaf(w1.x, x1.x, fmaf(w1.y, x1.y, fmaf(w1.z, x1.z, w1.w * x1.w)));
  return wreduce(s0 + s1);
}

__device__ __forceinline__ float dot512_wave(const float* __restrict__ a,
                                             const float* __restrict__ b, int lane) {
  const float4* b4 = (const float4*)b;
  return dotW(a, b4[lane], b4[lane + 64], lane);
}

__device__ __forceinline__ float dot128_wave(const float* __restrict__ a,
                                             const float* __restrict__ b, int lane) {
  const float2* a2 = (const float2*)a;
  const float2* b2 = (const float2*)b;
  float2 x = a2[lane], y = b2[lane];
  return wreduce(fmaf(x.x, y.x, x.y * y.y));
}

// ---------------- fused cooperative kernel ----------------
// Phase A: grid-stride wave-tasks (all GEMV-ish precompute, NO eager NE).
// grid.sync()
// Phase B: first 168 blocks act as the old k2 (20 pair slices + merge per b);
//          merge computes non_exist_out lazily, only for empty segments.
__global__ __launch_bounds__(256) void fused(
    const float* __restrict__ inp, const float* __restrict__ objmask,
    const float* __restrict__ TRt,
    const float* __restrict__ W_obj, const float* __restrict__ b_obj,
    const float* __restrict__ W_act, const float* __restrict__ b_act,
    const float* __restrict__ W_tr, const float* __restrict__ b_tr,
    const float* __restrict__ W_ne, const float* __restrict__ b_ne,
    const float* __restrict__ obj_emb, const float* __restrict__ act_emb,
    const int* __restrict__ AA, const int* __restrict__ aalut,
    float* __restrict__ out, float* __restrict__ ws)
{
  __shared__ float s_L[Kk*6];              // [k][t*2+h], h==0 half includes b_tr
  __shared__ float s_inv[NTRS];
  __shared__ unsigned s_seg[NCLS];
  __shared__ int s_sel[Kk], s_aa[Kk], s_C[Kk], s_vlist[Kk], s_pred[MO], s_T;
  __shared__ int s_miss[NCLS], s_nmiss;
  __shared__ __align__(16) float s_pool[Dd];

  const int tid = threadIdx.x;
  const int lane = tid & 63;

  // ================= Phase A =================
  {
    int gw = (blockIdx.x * 256 + tid) >> 6;
    for (int w = gw; w < T_INV; w += GRID * 4) {
      if (w < T_OBJ) {
        int b = w / (MO*NOBJ), r = w % (MO*NOBJ), o = r / NOBJ, c = r % NOBJ;
        float v = dot512_wave(W_obj + c*Dd, inp + (b*MO + o)*Dd, lane) + b_obj[c];
        if (!lane) out[OUT_OBJ + (b*MO + o)*NOBJ + c] = v;
      } else if (w < T_ACT) {
        int r = w - T_OBJ, b = r / Kk, k = r % Kk, o = k / NACT, a = k % NACT;
        float v = dot512_wave(W_act + a*Dd, inp + (b*MO + o)*Dd, lane) + b_act[a];
        if (!lane) out[OUT_ACT + b*Kk + k] = v;
      } else if (w < T_LINP) {
        int r = w - T_ACT, b = r / (MO*6), r2 = r % (MO*6), o = r2 / 6, th = r2 % 6;
        int t = th >> 1, h = th & 1;
        float v = dot512_wave(W_tr + t*FD + h*HALF, inp + (b*MO + o)*Dd, lane);
        if (!lane) ws[WS_LINP + (b*MO + o)*6 + th] = v;
      } else if (w < T_EO) {
        int r = w - T_LINP, oc = r / 6, th = r % 6, t = th >> 1, h = th & 1;
        float v = dot128_wave(W_tr + t*FD + h*HALF + Dd, obj_emb + oc*EMB, lane);
        if (!lane) ws[WS_EO + oc*6 + th] = v;
      } else if (w < T_EA) {
        int r = w - T_EO, a = r / 6, th = r % 6, t = th >> 1, h = th & 1;
        float v = dot128_wave(W_tr + t*FD + h*HALF + Dd + EMB, act_emb + a*EMB, lane);
        if (!lane) ws[WS_EA + a*6 + th] = v;
      } else {
        int t = w - T_EA;
        const float4* w4 = (const float4*)(W_tr + t*FD);
        float s = 0.f;
#pragma unroll
        for (int i = 0; i < 6; ++i) { float4 x = w4[lane + 64*i]; s += x.x + x.y + x.z + x.w; }
        s = wreduce(s);
        if (!lane) ws[WS_INV + t] = b_tr[t] - s;        // all-(-1) pair-row logit
      }
    }
  }

  __threadfence();
  cg::this_grid().sync();

  // ================= Phase B =================
  int bid = blockIdx.x;
  if (bid >= Bn * (NSLICE + 1)) return;
  int b = bid / (NSLICE + 1), slice = bid % (NSLICE + 1);

  // ---- preamble: per-block redundant argmax + selection (cheap, L2-hot) ----
  if (tid < MO) {                          // obj argmax, first-max
    const float* p = out + OUT_OBJ + (b*MO + tid)*NOBJ;
    float best = p[0]; int bi = 0;
#pragma unroll
    for (int c = 1; c < NOBJ; ++c) { float v = p[c]; if (v > best) { best = v; bi = c; } }
    s_pred[tid] = bi;
  } else if (tid >= 64 && tid < 64 + Kk) { // selection flags
    int k = tid - 64, o = k / NACT;
    int aa = AA[b*Kk + k];
    // sigmoid(x)>0.5 <=> x>0 ; pred_act==1.0 also needs mask==1.0
    int sel = (out[OUT_ACT + b*Kk + k] > 0.f) && (objmask[b*MO + o] == 1.0f) && (aa != -1);
    s_sel[k] = sel;
    s_aa[k] = sel ? aa : -1;
  } else if (tid >= 192 && tid < 192 + NTRS) {
    s_inv[tid - 192] = ws[WS_INV + (tid - 192)];
  }
  __syncthreads();
  for (int m = tid; m < Kk*6; m += 256) {  // assemble half-logits
    int k = m / 6, th = m % 6, t = th >> 1, h = th & 1;
    int o = k / NACT, a = k % NACT;
    float v = ws[WS_LINP + (b*MO + o)*6 + th] + ws[WS_EO + s_pred[o]*6 + th]
            + ws[WS_EA + a*6 + th];
    if (h == 0) v += b_tr[t];
    s_L[m] = v;
  }
  if (tid == 0) {
    int c = 0;
    for (int k = 0; k < Kk; ++k) { s_C[k] = c; c += s_sel[k]; }
    s_T = c;
    s_nmiss = 0;
  }
  __syncthreads();

  int T = s_T, Vtot = T*(T-1);

  if (slice < NSLICE) {
    // ---- pair block: closed-form packed destination, one pair per thread ----
    int q = slice*256 + tid;
    if (q < Pp) {
      float* plog = out + OUT_PLOG + (size_t)b*Pp*NTRS;
      float* ttgt = out + OUT_TTGT + (size_t)b*Pp*NTRS;
      int i = q / (Kk-1);
      int jj = q - i*(Kk-1);
      int j = jj + (jj >= i ? 1 : 0);
      int si = s_sel[i], sj = s_sel[j];
      // # valid pairs strictly before (i,j) in lex order -> O(1) packed position
      int vb = s_C[i]*(T-1) + (si ? (s_C[j] - (i < j ? 1 : 0)) : 0);
      bool valid = si && sj;
      int pos = valid ? vb : (Vtot + q - vb);
      float l0, l1, l2;
      if (valid) {
        l0 = s_L[i*6+0] + s_L[j*6+1];
        l1 = s_L[i*6+2] + s_L[j*6+3];
        l2 = s_L[i*6+4] + s_L[j*6+5];
      } else { l0 = s_inv[0]; l1 = s_inv[1]; l2 = s_inv[2]; }
      int ob = pos*3;
      plog[ob+0] = l0; plog[ob+1] = l1; plog[ob+2] = l2;
      if (valid) {
        const float* tr = TRt + (((size_t)b*Kk + i)*Kk + j)*NTRS;
        ttgt[ob+0] = tr[0]; ttgt[ob+1] = tr[1]; ttgt[ob+2] = tr[2];
      } else {
        ttgt[ob+0] = -1.f; ttgt[ob+1] = -1.f; ttgt[ob+2] = -1.f;
      }
    }
  } else {
    // ---- merge block: LDS segmax over VALID pairs only ----
    if (tid < Kk && s_sel[tid]) s_vlist[s_C[tid]] = tid;
    for (int c = tid; c < NCLS; c += 256) s_seg[c] = 0u;
    __syncthreads();
    for (int m = tid; m < Vtot; m += 256) {
      int vi = m / (T-1);
      int r = m - vi*(T-1);
      int vj = r + (r >= vi ? 1 : 0);
      int i = s_vlist[vi], j = s_vlist[vj];
      float l0 = s_L[i*6+0] + s_L[j*6+1];
      float l1 = s_L[i*6+2] + s_L[j*6+3];
      float l2 = s_L[i*6+4] + s_L[j*6+5];
      int base = (s_aa[i]*NAA + s_aa[j])*NTRS;
      atomicMax(&s_seg[aalut[base+0]], fmap(l0));   // ds_max, LDS-local
      atomicMax(&s_seg[aalut[base+1]], fmap(l1));
      atomicMax(&s_seg[aalut[base+2]], fmap(l2));
    }
    __syncthreads();
    // classes present -> segmax; classes absent -> collect for lazy NE
    for (int c = tid; c < NCLS; c += 256) {
      unsigned u = s_seg[c];
      if (u) out[OUT_FINAL + b*NCLS + c] = funmap(u);
      else s_miss[atomicAdd(&s_nmiss, 1)] = c;
    }
    __syncthreads();
    int nm = s_nmiss;
    if (nm) {
      // lazy non_exist_out: masked-mean pool once into LDS, then one wave-dot
      // per missing class. Expected nm ~ 0 with T~36; worst case nm=300 still ok.
      float msum = 0.f;
#pragma unroll
      for (int o = 0; o < MO; ++o) msum += objmask[b*MO + o];
      for (int d = tid; d < Dd; d += 256) {
        float acc = 0.f;
#pragma unroll
        for (int o = 0; o < MO; ++o)
          acc = fmaf(objmask[b*MO + o], inp[(b*MO + o)*Dd + d], acc);
        s_pool[d] = acc / msum;
      }
      __syncthreads();
      const float4* p4 = (const float4*)s_pool;
      float4 x0 = p4[lane], x1 = p4[lane + 64];
      int wv = tid >> 6;
      for (int m2 = wv; m2 < nm; m2 += 4) {
        int c = s_miss[m2];
        float v = dotW(W_ne + c*Dd, x0, x1, lane) + b_ne[c];
        if (!lane) out[OUT_FINAL + b*NCLS + c] = v;
      }
    }
  }
}

extern "C" void kernel_launch(void* const* d_in, const int* in_sizes, int n_in,
                              void* d_out, int out_size, void* d_ws, size_t ws_size,
                              hipStream_t stream) {
  (void)in_sizes; (void)n_in; (void)ws_size; (void)out_size;
  const float* inp      = (const float*)d_in[0];
  const float* objmask  = (const float*)d_in[1];
  const float* TRt      = (const float*)d_in[2];
  const float* W_obj    = (const float*)d_in[3];
  const float* b_obj    = (const float*)d_in[4];
  const float* W_act    = (const float*)d_in[5];
  const float* b_act    = (const float*)d_in[6];
  const float* W_tr     = (const float*)d_in[7];
  const float* b_tr     = (const float*)d_in[8];
  const float* W_ne     = (const float*)d_in[9];
  const float* b_ne     = (const float*)d_in[10];
  const float* obj_emb  = (const float*)d_in[11];
  const float* act_emb  = (const float*)d_in[12];
  const int*   AA       = (const int*)d_in[13];
  // d_in[14] = obj_act_lookup (eval-only)
  const int*   aalut    = (const int*)d_in[15];
  float* out = (float*)d_out;
  float* ws  = (float*)d_ws;

  void* args[] = {
    (void*)&inp, (void*)&objmask, (void*)&TRt,
    (void*)&W_obj, (void*)&b_obj, (void*)&W_act, (void*)&b_act,
    (void*)&W_tr, (void*)&b_tr, (void*)&W_ne, (void*)&b_ne,
    (void*)&obj_emb, (void*)&act_emb, (void*)&AA, (void*)&aalut,
    (void*)&out, (void*)&ws
  };
  hipLaunchCooperativeKernel((const void*)fused, dim3(GRID), dim3(256),
                             args, 0, stream);
}

// Round 2
// 91.543 us; speedup vs baseline: 1.6828x; 1.6828x over previous
//
#include <hip/hip_runtime.h>
#include <hip/hip_bf16.h>

// ---------------- problem constants ----------------
#define Bn    8
#define MO    12
#define Dd    512
#define NOBJ  37
#define NACT  6
#define NTRS  3
#define EMB   128
#define NAA   100
#define NCLS  300
#define Kk    72            // MO*NACT
#define Pp    5112          // Kk*(Kk-1)
#define HALF  768           // Dd + 2*EMB
#define FD    1536          // 2*HALF

// output layout (concatenated return order)
#define OUT_FINAL 0
#define OUT_PLOG  (Bn*NCLS)                       // 2400
#define OUT_TTGT  (OUT_PLOG + Bn*Pp*NTRS)         // 125088
#define OUT_ACT   (OUT_TTGT + Bn*Pp*NTRS)         // 247776
#define OUT_OBJ   (OUT_ACT + Bn*Kk)               // 248352

// ---------------- workspace layout (4-byte units) ----------------
// NE is computed lazily in the merge block; obj/act logits are read back
// from `out` by k2 (no duplicate ws copies).
#define WS_LINP 0                                 // [B,MO,6] (th = t*2+h)
#define WS_EO   (WS_LINP + Bn*MO*6)               // [NOBJ,6]        576
#define WS_EA   (WS_EO + NOBJ*6)                  // [NACT,6]        798
#define WS_INV  (WS_EA + NACT*6)                  // [3]             834

// monotonic float <-> uint; 0u is below any finite mapped value = "empty"
__device__ __forceinline__ unsigned fmap(float f) {
  unsigned u = __float_as_uint(f);
  return (u & 0x80000000u) ? ~u : (u | 0x80000000u);
}
__device__ __forceinline__ float funmap(unsigned u) {
  return __uint_as_float((u & 0x80000000u) ? (u & 0x7fffffffu) : ~u);
}

__device__ __forceinline__ float wreduce(float v) {
#pragma unroll
  for (int off = 32; off > 0; off >>= 1) v += __shfl_xor(v, off, 64);
  return v;
}

// 512-dot with x preloaded (lane holds float4 #lane, #(lane+64))
__device__ __forceinline__ float dotW(const float* __restrict__ wrow,
                                      float4 x0, float4 x1, int lane) {
  const float4* w4 = (const float4*)wrow;
  float4 w0 = w4[lane], w1 = w4[lane + 64];
  float s0 = fmaf(w0.x, x0.x, fmaf(w0.y, x0.y, fmaf(w0.z, x0.z, w0.w * x0.w)));
  float s1 = fmaf(w1.x, x1.x, fmaf(w1.y, x1.y, fmaf(w1.z, x1.z, w1.w * x1.w)));
  return wreduce(s0 + s1);
}

__device__ __forceinline__ float dot512_wave(const float* __restrict__ a,
                                             const float* __restrict__ b, int lane) {
  const float4* b4 = (const float4*)b;
  return dotW(a, b4[lane], b4[lane + 64], lane);
}

__device__ __forceinline__ float dot128_wave(const float* __restrict__ a,
                                             const float* __restrict__ b, int lane) {
  const float2* a2 = (const float2*)a;
  const float2* b2 = (const float2*)b;
  float2 x = a2[lane], y = b2[lane];
  return wreduce(fmaf(x.x, y.x, x.y * y.y));
}

// ---------------- K1: one minimal task per wave, zero dependencies ----------------
// (eager non_exist_out GEMV removed: 7365 -> 4965 wave-tasks)
#define W_OBJ_E  (Bn*MO*NOBJ)             // 3552
#define W_ACT_E  (W_OBJ_E + Bn*Kk)        // 4128
#define W_LINP_E (W_ACT_E + Bn*MO*6)      // 4704
#define W_EO_E   (W_LINP_E + NOBJ*6)      // 4926
#define W_EA_E   (W_EO_E + NACT*6)        // 4962
#define W_TOT    (W_EA_E + NTRS)          // 4965

__global__ __launch_bounds__(256) void k1(
    const float* __restrict__ inp,
    const float* __restrict__ W_obj, const float* __restrict__ b_obj,
    const float* __restrict__ W_act, const float* __restrict__ b_act,
    const float* __restrict__ W_tr, const float* __restrict__ b_tr,
    const float* __restrict__ obj_emb, const float* __restrict__ act_emb,
    float* __restrict__ out, float* __restrict__ ws)
{
  int gt = blockIdx.x * 256 + threadIdx.x;
  int w = gt >> 6, lane = gt & 63;

  if (w < W_OBJ_E) {
    int b = w / (MO*NOBJ), r = w % (MO*NOBJ), o = r / NOBJ, c = r % NOBJ;
    float v = dot512_wave(W_obj + c*Dd, inp + (b*MO + o)*Dd, lane) + b_obj[c];
    if (!lane) out[OUT_OBJ + (b*MO + o)*NOBJ + c] = v;
  } else if (w < W_ACT_E) {
    int r = w - W_OBJ_E, b = r / Kk, k = r % Kk, o = k / NACT, a = k % NACT;
    float v = dot512_wave(W_act + a*Dd, inp + (b*MO + o)*Dd, lane) + b_act[a];
    if (!lane) out[OUT_ACT + b*Kk + k] = v;
  } else if (w < W_LINP_E) {
    int r = w - W_ACT_E, b = r / (MO*6), r2 = r % (MO*6), o = r2 / 6, th = r2 % 6;
    int t = th >> 1, h = th & 1;
    float v = dot512_wave(W_tr + t*FD + h*HALF, inp + (b*MO + o)*Dd, lane);
    if (!lane) ws[WS_LINP + (b*MO + o)*6 + th] = v;
  } else if (w < W_EO_E) {
    int r = w - W_LINP_E, oc = r / 6, th = r % 6, t = th >> 1, h = th & 1;
    float v = dot128_wave(W_tr + t*FD + h*HALF + Dd, obj_emb + oc*EMB, lane);
    if (!lane) ws[WS_EO + oc*6 + th] = v;
  } else if (w < W_TOT) {
    if (w < W_EA_E) {
      int r = w - W_EO_E, a = r / 6, th = r % 6, t = th >> 1, h = th & 1;
      float v = dot128_wave(W_tr + t*FD + h*HALF + Dd + EMB, act_emb + a*EMB, lane);
      if (!lane) ws[WS_EA + a*6 + th] = v;
    } else {
      int t = w - W_EA_E;
      const float4* w4 = (const float4*)(W_tr + t*FD);
      float s = 0.f;
#pragma unroll
      for (int i = 0; i < 6; ++i) { float4 x = w4[lane + 64*i]; s += x.x + x.y + x.z + x.w; }
      s = wreduce(s);
      if (!lane) ws[WS_INV + t] = b_tr[t] - s;        // all-(-1) pair-row logit
    }
  }
}

// ---------------- K2: pair blocks (slice 0..19) + concurrent merge block (20) ----
// Merge depends only on K1 outputs; LDS segmax over valid pairs only; the
// non_exist fallback is computed lazily, only for classes with empty segments
// (expected ~0 of them at T~36).
#define NSLICE 20

__global__ __launch_bounds__(256) void k2(
    const float* __restrict__ inp, const float* __restrict__ objmask,
    const float* __restrict__ TRt, const float* __restrict__ b_tr,
    const float* __restrict__ W_ne, const float* __restrict__ b_ne,
    const int* __restrict__ AA, const int* __restrict__ aalut,
    float* __restrict__ out, float* __restrict__ ws)
{
  __shared__ float s_L[Kk*6];              // [k][t*2+h], h==0 half includes b_tr
  __shared__ float s_inv[NTRS];
  __shared__ unsigned s_seg[NCLS];
  __shared__ int s_sel[Kk], s_aa[Kk], s_C[Kk], s_vlist[Kk], s_pred[MO], s_T;
  __shared__ int s_miss[NCLS], s_nmiss;
  __shared__ __align__(16) float s_pool[Dd];

  int b = blockIdx.x / (NSLICE + 1), slice = blockIdx.x % (NSLICE + 1);
  int tid = threadIdx.x, lane = tid & 63;

  // ---- preamble: per-block redundant argmax + selection (cheap, L2-hot) ----
  if (tid < MO) {                          // obj argmax, first-max
    const float* p = out + OUT_OBJ + (b*MO + tid)*NOBJ;
    float best = p[0]; int bi = 0;
#pragma unroll
    for (int c = 1; c < NOBJ; ++c) { float v = p[c]; if (v > best) { best = v; bi = c; } }
    s_pred[tid] = bi;
  } else if (tid >= 64 && tid < 64 + Kk) { // selection flags
    int k = tid - 64, o = k / NACT;
    int aa = AA[b*Kk + k];
    // sigmoid(x)>0.5 <=> x>0 ; pred_act==1.0 also needs mask==1.0
    int sel = (out[OUT_ACT + b*Kk + k] > 0.f) && (objmask[b*MO + o] == 1.0f) && (aa != -1);
    s_sel[k] = sel;
    s_aa[k] = sel ? aa : -1;
  } else if (tid >= 192 && tid < 192 + NTRS) {
    s_inv[tid - 192] = ws[WS_INV + (tid - 192)];
  }
  __syncthreads();
  for (int m = tid; m < Kk*6; m += 256) {  // assemble half-logits
    int k = m / 6, th = m % 6, t = th >> 1, h = th & 1;
    int o = k / NACT, a = k % NACT;
    float v = ws[WS_LINP + (b*MO + o)*6 + th] + ws[WS_EO + s_pred[o]*6 + th]
            + ws[WS_EA + a*6 + th];
    if (h == 0) v += b_tr[t];
    s_L[m] = v;
  }
  if (tid == 0) {
    int c = 0;
    for (int k = 0; k < Kk; ++k) { s_C[k] = c; c += s_sel[k]; }
    s_T = c;
    s_nmiss = 0;
  }
  __syncthreads();

  int T = s_T, Vtot = T*(T-1);

  if (slice < NSLICE) {
    // ---- pair block: closed-form packed destination, one pair per thread ----
    int q = slice*256 + tid;
    if (q < Pp) {
      float* plog = out + OUT_PLOG + (size_t)b*Pp*NTRS;
      float* ttgt = out + OUT_TTGT + (size_t)b*Pp*NTRS;
      int i = q / (Kk-1);
      int jj = q - i*(Kk-1);
      int j = jj + (jj >= i ? 1 : 0);
      int si = s_sel[i], sj = s_sel[j];
      // # valid pairs strictly before (i,j) in lex order -> O(1) packed position
      int vb = s_C[i]*(T-1) + (si ? (s_C[j] - (i < j ? 1 : 0)) : 0);
      bool valid = si && sj;
      int pos = valid ? vb : (Vtot + q - vb);
      float l0, l1, l2;
      if (valid) {
        l0 = s_L[i*6+0] + s_L[j*6+1];
        l1 = s_L[i*6+2] + s_L[j*6+3];
        l2 = s_L[i*6+4] + s_L[j*6+5];
      } else { l0 = s_inv[0]; l1 = s_inv[1]; l2 = s_inv[2]; }
      int ob = pos*3;
      plog[ob+0] = l0; plog[ob+1] = l1; plog[ob+2] = l2;
      if (valid) {
        const float* tr = TRt + (((size_t)b*Kk + i)*Kk + j)*NTRS;
        ttgt[ob+0] = tr[0]; ttgt[ob+1] = tr[1]; ttgt[ob+2] = tr[2];
      } else {
        ttgt[ob+0] = -1.f; ttgt[ob+1] = -1.f; ttgt[ob+2] = -1.f;
      }
    }
  } else {
    // ---- merge block: LDS segmax over VALID pairs only (T(T-1) ~ 1300 avg) ----
    if (tid < Kk && s_sel[tid]) s_vlist[s_C[tid]] = tid;
    for (int c = tid; c < NCLS; c += 256) s_seg[c] = 0u;
    __syncthreads();
    for (int m = tid; m < Vtot; m += 256) {
      int vi = m / (T-1);
      int r = m - vi*(T-1);
      int vj = r + (r >= vi ? 1 : 0);
      int i = s_vlist[vi], j = s_vlist[vj];
      float l0 = s_L[i*6+0] + s_L[j*6+1];
      float l1 = s_L[i*6+2] + s_L[j*6+3];
      float l2 = s_L[i*6+4] + s_L[j*6+5];
      int base = (s_aa[i]*NAA + s_aa[j])*NTRS;
      atomicMax(&s_seg[aalut[base+0]], fmap(l0));   // ds_max, LDS-local
      atomicMax(&s_seg[aalut[base+1]], fmap(l1));
      atomicMax(&s_seg[aalut[base+2]], fmap(l2));
    }
    __syncthreads();
    // classes present -> segmax; classes absent -> collect for lazy NE
    for (int c = tid; c < NCLS; c += 256) {
      unsigned u = s_seg[c];
      if (u) out[OUT_FINAL + b*NCLS + c] = funmap(u);
      else s_miss[atomicAdd(&s_nmiss, 1)] = c;
    }
    __syncthreads();
    int nm = s_nmiss;
    if (nm) {
      // lazy non_exist_out: masked-mean pool once into LDS, then one wave-dot
      // per missing class. Expected nm ~ 0 with T~36; worst case nm=300 still ok.
      float msum = 0.f;
#pragma unroll
      for (int o = 0; o < MO; ++o) msum += objmask[b*MO + o];
      for (int d = tid; d < Dd; d += 256) {
        float acc = 0.f;
#pragma unroll
        for (int o = 0; o < MO; ++o)
          acc = fmaf(objmask[b*MO + o], inp[(b*MO + o)*Dd + d], acc);
        s_pool[d] = acc / msum;
      }
      __syncthreads();
      const float4* p4 = (const float4*)s_pool;
      float4 x0 = p4[lane], x1 = p4[lane + 64];
      int wv = tid >> 6;
      for (int m2 = wv; m2 < nm; m2 += 4) {
        int c = s_miss[m2];
        float v = dotW(W_ne + c*Dd, x0, x1, lane) + b_ne[c];
        if (!lane) out[OUT_FINAL + b*NCLS + c] = v;
      }
    }
  }
}

extern "C" void kernel_launch(void* const* d_in, const int* in_sizes, int n_in,
                              void* d_out, int out_size, void* d_ws, size_t ws_size,
                              hipStream_t stream) {
  (void)in_sizes; (void)n_in; (void)ws_size; (void)out_size;
  const float* inp      = (const float*)d_in[0];
  const float* objmask  = (const float*)d_in[1];
  const float* TRt      = (const float*)d_in[2];
  const float* W_obj    = (const float*)d_in[3];
  const float* b_obj    = (const float*)d_in[4];
  const float* W_act    = (const float*)d_in[5];
  const float* b_act    = (const float*)d_in[6];
  const float* W_tr     = (const float*)d_in[7];
  const float* b_tr     = (const float*)d_in[8];
  const float* W_ne     = (const float*)d_in[9];
  const float* b_ne     = (const float*)d_in[10];
  const float* obj_emb  = (const float*)d_in[11];
  const float* act_emb  = (const float*)d_in[12];
  const int*   AA       = (const int*)d_in[13];
  // d_in[14] = obj_act_lookup (eval-only)
  const int*   aalut    = (const int*)d_in[15];
  float* out = (float*)d_out;
  float* ws  = (float*)d_ws;

  hipLaunchKernelGGL(k1, dim3((W_TOT + 3) / 4), dim3(256), 0, stream,
                     inp, W_obj, b_obj, W_act, b_act, W_tr, b_tr,
                     obj_emb, act_emb, out, ws);
  hipLaunchKernelGGL(k2, dim3(Bn * (NSLICE + 1)), dim3(256), 0, stream,
                     inp, objmask, TRt, b_tr, W_ne, b_ne, AA, aalut, out, ws);
}